// Round 1
// baseline (210.925 us; speedup 1.0000x reference)
//
#include <hip/hip_runtime.h>
#include <hip/hip_bf16.h>

#define VDIM 50257
#define EDIM 128
#define MROWS 2048
#define KMAIN 50240            // 1570 * 32, multiple of 64; tail of 17 handled in fp32
#define KTAIL 17               // VDIM - KMAIN
#define STEPS_TOTAL 1570
#define SPLIT 32
#define STEPS_PER_CHUNK 50     // ceil(1570/32); last chunk does 20
#define BM 128

using short8_t = __attribute__((ext_vector_type(8))) short;
using float4_t = __attribute__((ext_vector_type(4))) float;

static __device__ __forceinline__ short f2bf(float f) {
    union { __hip_bfloat16 h; short s; } u;
    u.h = __float2bfloat16(f);
    return u.s;
}

// W (VDIM x EDIM fp32, row-major) -> Wt (EDIM x KMAIN bf16, row-major).
// Only k < KMAIN is needed by the MFMA kernel; tail handled in k_reduce.
__global__ __launch_bounds__(256) void k_transpose(const float* __restrict__ W,
                                                   short* __restrict__ Wt) {
    __shared__ float tile[64][132];   // +4 pad: transposed reads spread banks
    const int t = threadIdx.x;
    const int v0 = blockIdx.x * 64;   // KMAIN/64 = 785 blocks, exact
    #pragma unroll
    for (int p = 0; p < 32; ++p) {
        int idx = p * 256 + t;
        int r = idx >> 7, c = idx & 127;
        tile[r][c] = W[(size_t)(v0 + r) * EDIM + c];
    }
    __syncthreads();
    const int e = t >> 1, half = t & 1;
    short* dst = Wt + (size_t)e * KMAIN + v0 + half * 32;  // 16B aligned
    #pragma unroll
    for (int i = 0; i < 4; ++i) {
        short8_t pk;
        #pragma unroll
        for (int j = 0; j < 8; ++j) pk[j] = f2bf(tile[half * 32 + i * 8 + j][e]);
        *reinterpret_cast<short8_t*>(dst + i * 8) = pk;
    }
}

// Split-K bf16 MFMA GEMM. Grid = (MROWS/BM) * SPLIT = 512 blocks of 256 threads.
// bid = s + SPLIT*mt  -> same-K-chunk blocks land on the same XCD (bid%8 == s%8).
// Each wave: 32 rows x 128 cols (2 rowfrags x 8 colfrags of 16x16x32).
// No LDS: A loaded as per-lane dwords (rows only 4B-aligned), Wt as aligned 16B.
__global__ __launch_bounds__(256) void k_main(const float* __restrict__ A,
                                              const short* __restrict__ Wt,
                                              float* __restrict__ P) {
    const int bid = blockIdx.x;
    const int s   = bid & (SPLIT - 1);
    const int mt  = bid >> 5;
    const int lane = threadIdx.x & 63;
    const int wv   = threadIdx.x >> 6;

    const int step0  = s * STEPS_PER_CHUNK;
    const int nsteps = min(STEPS_PER_CHUNK, STEPS_TOTAL - step0);
    const int k0     = step0 * 32;

    const int rl   = lane & 15;   // row/col within fragment
    const int kg   = lane >> 4;   // k-group 0..3
    const int koff = kg * 8;

    const int r0 = mt * BM + wv * 32 + rl;

    const float* a0 = A + (size_t)r0 * VDIM + k0 + koff;
    const float* a1 = a0 + (size_t)16 * VDIM;

    const short* wp[8];
    {
        const short* wbase = Wt + (size_t)rl * KMAIN + k0 + koff;
        #pragma unroll
        for (int cf = 0; cf < 8; ++cf) wp[cf] = wbase + (size_t)cf * 16 * KMAIN;
    }

    float4_t acc[2][8];
    #pragma unroll
    for (int i = 0; i < 2; ++i)
        #pragma unroll
        for (int j = 0; j < 8; ++j) acc[i][j] = (float4_t){0.f, 0.f, 0.f, 0.f};

    for (int it = 0; it < nsteps; ++it) {
        short8_t bw[8];
        #pragma unroll
        for (int cf = 0; cf < 8; ++cf)
            bw[cf] = *reinterpret_cast<const short8_t*>(wp[cf]);  // 16B aligned

        float a0f[8], a1f[8];
        #pragma unroll
        for (int j = 0; j < 8; ++j) { a0f[j] = a0[j]; a1f[j] = a1[j]; }

        short8_t af0, af1;
        #pragma unroll
        for (int j = 0; j < 8; ++j) { af0[j] = f2bf(a0f[j]); af1[j] = f2bf(a1f[j]); }

        #pragma unroll
        for (int cf = 0; cf < 8; ++cf) {
            acc[0][cf] = __builtin_amdgcn_mfma_f32_16x16x32_bf16(af0, bw[cf], acc[0][cf], 0, 0, 0);
            acc[1][cf] = __builtin_amdgcn_mfma_f32_16x16x32_bf16(af1, bw[cf], acc[1][cf], 0, 0, 0);
        }

        a0 += 32; a1 += 32;
        #pragma unroll
        for (int cf = 0; cf < 8; ++cf) wp[cf] += 32;
    }

    // Partial write: C/D layout col = lane&15, row = (lane>>4)*4 + j  [m89-verified]
    float* pout = P + ((size_t)s * MROWS + (size_t)mt * BM + (size_t)wv * 32) * EDIM;
    #pragma unroll
    for (int rf = 0; rf < 2; ++rf)
        #pragma unroll
        for (int cf = 0; cf < 8; ++cf)
            #pragma unroll
            for (int j = 0; j < 4; ++j) {
                int rr = rf * 16 + kg * 4 + j;
                int cc = cf * 16 + rl;
                pout[(size_t)rr * EDIM + cc] = acc[rf][cf][j];
            }
}

// out = bias + sum of SPLIT partials + fp32 K-tail (k in [KMAIN, VDIM)).
__global__ __launch_bounds__(256) void k_reduce(const float* __restrict__ P,
                                                const float* __restrict__ A,
                                                const float* __restrict__ W,
                                                const float* __restrict__ bias,
                                                float* __restrict__ out) {
    const int idx = blockIdx.x * 256 + threadIdx.x;  // grid covers MROWS*EDIM
    const int m = idx >> 7, e = idx & 127;
    float acc = bias[e];
    #pragma unroll
    for (int j = 0; j < KTAIL; ++j)
        acc += A[(size_t)m * VDIM + KMAIN + j] * W[(size_t)(KMAIN + j) * EDIM + e];
    float psum = 0.f;
    #pragma unroll
    for (int p = 0; p < SPLIT; ++p)
        psum += P[(size_t)p * (MROWS * EDIM) + idx];
    out[idx] = acc + psum;
}

// Emergency fallback if workspace is too small: plain fp32, deterministic.
__global__ __launch_bounds__(256) void k_naive(const float* __restrict__ A,
                                               const float* __restrict__ W,
                                               const float* __restrict__ bias,
                                               float* __restrict__ out) {
    const int e  = threadIdx.x & 127;
    const int mi = threadIdx.x >> 7;
    const int m0 = blockIdx.x * 8 + mi;
    float acc[4] = {0.f, 0.f, 0.f, 0.f};
    for (int k = 0; k < VDIM; ++k) {
        float w = W[(size_t)k * EDIM + e];
        #pragma unroll
        for (int q = 0; q < 4; ++q)
            acc[q] += A[(size_t)(m0 + q * 2) * VDIM + k] * w;
    }
    #pragma unroll
    for (int q = 0; q < 4; ++q)
        out[(size_t)(m0 + q * 2) * EDIM + e] = acc[q] + bias[e];
}

extern "C" void kernel_launch(void* const* d_in, const int* in_sizes, int n_in,
                              void* d_out, int out_size, void* d_ws, size_t ws_size,
                              hipStream_t stream) {
    const float* A    = (const float*)d_in[0];  // (16,128,50257) fp32
    const float* W    = (const float*)d_in[1];  // (50257,128) fp32
    const float* bias = (const float*)d_in[2];  // (128,) fp32
    float* out = (float*)d_out;                 // (16,128,128) fp32

    const size_t WT_BYTES = (size_t)EDIM * KMAIN * sizeof(short);          // 12.86 MB
    const size_t P_BYTES  = (size_t)SPLIT * MROWS * EDIM * sizeof(float);  // 33.55 MB

    if (ws_size >= WT_BYTES + P_BYTES) {
        short* Wt = (short*)d_ws;
        float* P  = (float*)((char*)d_ws + WT_BYTES);
        k_transpose<<<KMAIN / 64, 256, 0, stream>>>(W, Wt);
        k_main<<<(MROWS / BM) * SPLIT, 256, 0, stream>>>(A, Wt, P);
        k_reduce<<<(MROWS * EDIM) / 256, 256, 0, stream>>>(P, A, W, bias, out);
    } else {
        k_naive<<<MROWS / 8, 256, 0, stream>>>(A, W, bias, out);
    }
}